// Round 2
// baseline (2175.016 us; speedup 1.0000x reference)
//
#include <hip/hip_runtime.h>
#include <hip/hip_bf16.h>
#include <stdint.h>

#define AS1 __attribute__((address_space(1)))
#define AS3 __attribute__((address_space(3)))

typedef short s16x8 __attribute__((ext_vector_type(8)));
typedef float f32x16 __attribute__((ext_vector_type(16)));
typedef __bf16 bf16x8_t __attribute__((ext_vector_type(8)));

union ABFrag { bf16x8_t h; s16x8 s; };

__device__ __forceinline__ ushort f2b_rne(float f){
  uint32_t u = __float_as_uint(f);
  u += 0x7fffu + ((u >> 16) & 1u);
  return (ushort)(u >> 16);
}

// ---------------------------------------------------------------------------
// Pack W: fp32 [A=128][N=64][M=64][O=64] -> bf16 fragment-ordered stream.
// ws bf16 element index:
//   (n*64+m)*8192 + (s*4+wn)*512 + (g*32+la)*8 + i
//     = bf16( W[a=wn*32+la][n][m][o=s*16+g*8+i] )
// ---------------------------------------------------------------------------
__global__ __launch_bounds__(256) void pack_w_kernel(const float* __restrict__ W,
                                                     ushort* __restrict__ wsp){
  const int u  = blockIdx.x * 256 + threadIdx.x;   // (n*64+m)*128 + a
  const int a  = u & 127;
  const int nm = u >> 7;            // n*64 + m
  const int n  = nm >> 6;
  const int m  = nm & 63;
  const float* src = W + ((size_t)a << 18) + ((size_t)n << 12) + ((size_t)m << 6);
  ushort* dst = wsp + (size_t)nm * 8192;
  const int wn = a >> 5, la = a & 31;
  #pragma unroll
  for (int s = 0; s < 4; ++s){
    #pragma unroll
    for (int g = 0; g < 2; ++g){
      const float4 f0 = *(const float4*)(src + s*16 + g*8);
      const float4 f1 = *(const float4*)(src + s*16 + g*8 + 4);
      uint4 o;
      o.x = (uint32_t)f2b_rne(f0.x) | ((uint32_t)f2b_rne(f0.y) << 16);
      o.y = (uint32_t)f2b_rne(f0.z) | ((uint32_t)f2b_rne(f0.w) << 16);
      o.z = (uint32_t)f2b_rne(f1.x) | ((uint32_t)f2b_rne(f1.y) << 16);
      o.w = (uint32_t)f2b_rne(f1.z) | ((uint32_t)f2b_rne(f1.w) << 16);
      *(uint4*)(dst + (s*4 + wn)*512 + (g*32 + la)*8) = o;
    }
  }
}

// ---------------------------------------------------------------------------
// GEMM: out[b,a] += sum_n x1[b,n] * ( sum_{m,o} (x2[b,m]*x3[b,o]) * W[a,n,m,o] )
// 256 rows/block, 8 waves x 32 rows, BN=128 (full A), split-K=8 over n
// -> 512 blocks = 2 blocks/CU (LDS 68KB, VGPR<=128) for cross-block overlap.
// A-operand generated in registers (rank-1: x2[m]-scalar * x3 row regs).
// B staged via global_load_lds, double-buffered, 1 barrier/iter.
// mfma_f32_32x32x16_bf16; D layout: col=lane&31, row=(r&3)+8*(r>>2)+4*(lane>>5).
// ---------------------------------------------------------------------------
__global__ __launch_bounds__(512, 4) void trilinear_gemm_kernel(
    const float* __restrict__ x1g, const float* __restrict__ x2g,
    const float* __restrict__ x3g, const ushort* __restrict__ wsp,
    const float* __restrict__ biasg, float* __restrict__ outg){

  __shared__ __align__(16) char Bbuf[2 * 16384];   // 32 KB: W double-buffer
  __shared__ ushort x2s[256 * 64];                 // 32 KB
  __shared__ ushort x1s[256 * 8];                  //  4 KB: only this block's n-range

  const int tid  = threadIdx.x;
  const int wave = tid >> 6;
  const int lane = tid & 63;
  const int la   = lane & 31;
  const int lg   = lane >> 5;

  const int bid      = blockIdx.x;
  const int nsplit   = bid & 7;     // == XCD id under round-robin dispatch -> all
  const int row_tile = bid >> 3;    //    blocks on one XCD stream the same W region
  const int row0     = row_tile * 256;
  const int n0       = nsplit * 8;

  // ---- stage x2 tile to LDS as bf16, staggered columns (conflict-free reads)
  #pragma unroll
  for (int j = 0; j < 32; ++j){
    const int e = tid + 512 * j;
    const int r = e >> 6, c = e & 63;
    const int cc = (c + r) & 63;
    x2s[r*64 + cc] = f2b_rne(x2g[(size_t)row0*64 + e]);
  }
  // ---- stage x1 (only columns n0..n0+7)
  #pragma unroll
  for (int j = 0; j < 4; ++j){
    const int e = tid + 512 * j;            // r*8 + c
    const int r = e >> 3, c = e & 7;
    x1s[e] = f2b_rne(x1g[(size_t)(row0 + r)*64 + n0 + c]);
  }

  // ---- this lane's x3 row -> 32 fp32 registers (its k-group's o values)
  const int arow = row0 + wave*32 + la;
  float x3r[32];
  #pragma unroll
  for (int s = 0; s < 4; ++s){
    const float4 p0 = *(const float4*)(x3g + (size_t)arow*64 + s*16 + lg*8);
    const float4 p1 = *(const float4*)(x3g + (size_t)arow*64 + s*16 + lg*8 + 4);
    x3r[s*8+0]=p0.x; x3r[s*8+1]=p0.y; x3r[s*8+2]=p0.z; x3r[s*8+3]=p0.w;
    x3r[s*8+4]=p1.x; x3r[s*8+5]=p1.y; x3r[s*8+6]=p1.z; x3r[s*8+7]=p1.w;
  }

  f32x16 tacc[4], macc[4];
  #pragma unroll
  for (int wn = 0; wn < 4; ++wn){ tacc[wn] = 0.f; macc[wn] = 0.f; }

  const ushort* wbase = wsp + (size_t)n0 * 64 * 8192;

  // prologue: stage K-block 0 into buffer 0 (linear: dst = wave base + lane*16)
  {
    const char* sp = (const char*)wbase + wave*2048 + lane*16;
    char* dp = Bbuf + wave*2048;
    __builtin_amdgcn_global_load_lds((const AS1 uint32_t*)sp,        (AS3 uint32_t*)dp,        16, 0, 0);
    __builtin_amdgcn_global_load_lds((const AS1 uint32_t*)(sp+1024), (AS3 uint32_t*)(dp+1024), 16, 0, 0);
  }
  __syncthreads();   // covers x1s/x2s stores + block-0 DMA (vmcnt(0) at barrier)

  const int rl = wave*32 + la;
  int cur = 0;

  for (int blk = 0; blk < 512; ++blk){           // 8 n per block x 64 m
    // stage next K-block into the other buffer (lands by next barrier)
    if (blk + 1 < 512){
      const char* sp = (const char*)wbase + (size_t)(blk + 1) * 16384 + wave*2048 + lane*16;
      char* dp = Bbuf + (cur ^ 1) * 16384 + wave*2048;
      __builtin_amdgcn_global_load_lds((const AS1 uint32_t*)sp,        (AS3 uint32_t*)dp,        16, 0, 0);
      __builtin_amdgcn_global_load_lds((const AS1 uint32_t*)(sp+1024), (AS3 uint32_t*)(dp+1024), 16, 0, 0);
    }

    // A-fragments: U[row][o] = x2[row][m] * x3[row][o], bf16
    const int m = blk & 63;
    const uint32_t cb = x2s[rl*64 + ((m + rl) & 63)];
    const float c = __uint_as_float(cb << 16);

    ABFrag af[4];
    #pragma unroll
    for (int s = 0; s < 4; ++s){
      #pragma unroll
      for (int i = 0; i < 8; ++i)
        af[s].h[i] = (__bf16)(c * x3r[s*8 + i]);
    }

    // 16 MFMAs: 4 K-steps x 4 col-fragments
    const char* bb = Bbuf + cur * 16384 + (lane << 4);
    #pragma unroll
    for (int s = 0; s < 4; ++s){
      #pragma unroll
      for (int wn = 0; wn < 4; ++wn){
        const s16x8 bf = *(const s16x8*)(bb + ((s*4 + wn) << 10));
        tacc[wn] = __builtin_amdgcn_mfma_f32_32x32x16_bf16(af[s].s, bf, tacc[wn], 0, 0, 0);
      }
    }

    // n boundary: fold tacc into macc scaled by x1[row][n], reset tacc
    if (m == 63){
      const int nc = blk >> 6;                   // 0..7 within this split
      #pragma unroll
      for (int r = 0; r < 16; ++r){
        const int rloc = wave*32 + (r & 3) + 8*(r >> 2) + 4*lg;
        const uint32_t xb = x1s[rloc*8 + nc];    // 2 addresses/wave -> broadcast
        const float xv = __uint_as_float(xb << 16);
        #pragma unroll
        for (int wn = 0; wn < 4; ++wn){
          macc[wn][r] += xv * tacc[wn][r];
          tacc[wn][r] = 0.f;
        }
      }
    }
    __syncthreads();
    cur ^= 1;
  }

  // ---- epilogue: atomic accumulate split-K partials; split 0 carries bias
  #pragma unroll
  for (int wn = 0; wn < 4; ++wn){
    const int col = wn*32 + la;
    const float bv = (nsplit == 0) ? biasg[col] : 0.f;
    #pragma unroll
    for (int r = 0; r < 16; ++r){
      const int row = row0 + wave*32 + (r & 3) + 8*(r >> 2) + 4*lg;
      atomicAdd(outg + (size_t)row*128 + col, macc[wn][r] + bv);
    }
  }
}

// ---------------------------------------------------------------------------
extern "C" void kernel_launch(void* const* d_in, const int* in_sizes, int n_in,
                              void* d_out, int out_size, void* d_ws, size_t ws_size,
                              hipStream_t stream){
  const float* x1   = (const float*)d_in[0];
  const float* x2   = (const float*)d_in[1];
  const float* x3   = (const float*)d_in[2];
  const float* W    = (const float*)d_in[3];
  const float* bias = (const float*)d_in[4];
  float* out = (float*)d_out;

  // d_out is re-poisoned before every launch: zero it (split-K accumulates on top)
  hipMemsetAsync(d_out, 0, (size_t)16384 * 128 * sizeof(float), stream);

  // need 64 MB of scratch for the bf16-packed W
  if (ws_size < (size_t)64 * 1024 * 1024) return;  // leaves zeros -> diagnostic absmax ~246

  ushort* wsp = (ushort*)d_ws;
  pack_w_kernel<<<2048, 256, 0, stream>>>(W, wsp);
  trilinear_gemm_kernel<<<512, 512, 0, stream>>>(x1, x2, x3, wsp, bias, out);
}

// Round 3
// 1087.342 us; speedup vs baseline: 2.0003x; 2.0003x over previous
//
#include <hip/hip_runtime.h>
#include <hip/hip_bf16.h>
#include <stdint.h>

#define AS1 __attribute__((address_space(1)))
#define AS3 __attribute__((address_space(3)))

typedef short s16x8 __attribute__((ext_vector_type(8)));
typedef float f32x16 __attribute__((ext_vector_type(16)));
typedef __bf16 bf16x8_t __attribute__((ext_vector_type(8)));

union ABFrag { bf16x8_t h; s16x8 s; };

__device__ __forceinline__ ushort f2b_rne(float f){
  uint32_t u = __float_as_uint(f);
  u += 0x7fffu + ((u >> 16) & 1u);
  return (ushort)(u >> 16);
}

// ---------------------------------------------------------------------------
// Pack W: fp32 [A=128][N=64][M=64][O=64] -> bf16 fragment-ordered stream.
// ws bf16 element index:
//   (n*64+m)*8192 + (s*4+wn)*512 + (g*32+la)*8 + i
//     = bf16( W[a=wn*32+la][n][m][o=s*16+g*8+i] )
// ---------------------------------------------------------------------------
__global__ __launch_bounds__(256) void pack_w_kernel(const float* __restrict__ W,
                                                     ushort* __restrict__ wsp){
  const int u  = blockIdx.x * 256 + threadIdx.x;   // (n*64+m)*128 + a
  const int a  = u & 127;
  const int nm = u >> 7;            // n*64 + m
  const int n  = nm >> 6;
  const int m  = nm & 63;
  const float* src = W + ((size_t)a << 18) + ((size_t)n << 12) + ((size_t)m << 6);
  ushort* dst = wsp + (size_t)nm * 8192;
  const int wn = a >> 5, la = a & 31;
  #pragma unroll
  for (int s = 0; s < 4; ++s){
    #pragma unroll
    for (int g = 0; g < 2; ++g){
      const float4 f0 = *(const float4*)(src + s*16 + g*8);
      const float4 f1 = *(const float4*)(src + s*16 + g*8 + 4);
      uint4 o;
      o.x = (uint32_t)f2b_rne(f0.x) | ((uint32_t)f2b_rne(f0.y) << 16);
      o.y = (uint32_t)f2b_rne(f0.z) | ((uint32_t)f2b_rne(f0.w) << 16);
      o.z = (uint32_t)f2b_rne(f1.x) | ((uint32_t)f2b_rne(f1.y) << 16);
      o.w = (uint32_t)f2b_rne(f1.z) | ((uint32_t)f2b_rne(f1.w) << 16);
      *(uint4*)(dst + (s*4 + wn)*512 + (g*32 + la)*8) = o;
    }
  }
}

// ---------------------------------------------------------------------------
// out[b,a] = sum_{n,m,o} x1[b,n] x2[b,m] x3[b,o] W[a,n,m,o] + bias[a]
// A-fragment = bf16(x1[n]*x2[m]*x3[o]) generated in registers (x1 folded in,
// no second accumulator). BM=512: 8 waves x 64 rows (2 row-groups/wave) so
// each B ds_read_b128 feeds TWO MFMAs (LDS read = 50% of MFMA budget).
// W quad-buffered in LDS, DMA issued 2 iters ahead, counted vmcnt(4) + raw
// s_barrier (no vmcnt(0) drain in main loop). 256 blocks = 1/CU, splitK=8,
// nsplit = bid&7 = XCD -> 32 lockstep blocks/XCD share one 8MB W octant in L2.
// mfma_f32_32x32x16_bf16; D layout: col=lane&31, row=(r&3)+8*(r>>2)+4*(lane>>5).
// ---------------------------------------------------------------------------
__global__ __launch_bounds__(512, 2) void trilinear_gemm_kernel(
    const float* __restrict__ x1g, const float* __restrict__ x2g,
    const float* __restrict__ x3g, const ushort* __restrict__ wsp,
    const float* __restrict__ biasg, float* __restrict__ outg){

  __shared__ __align__(16) char Bbuf[4 * 16384];   // 64 KB: W quad-buffer
  __shared__ ushort x2s[512 * 64];                 // 64 KB, staggered cols
  __shared__ ushort x1s[512 * 8];                  //  8 KB: this block's n-range

  const int tid  = threadIdx.x;
  const int wave = tid >> 6;
  const int lane = tid & 63;
  const int la   = lane & 31;
  const int lg   = lane >> 5;

  const int bid    = blockIdx.x;
  const int nsplit = bid & 7;       // == XCD id under round-robin dispatch
  const int row0   = (bid >> 3) * 512;
  const int n0     = nsplit * 8;

  // ---- stage x2 tile (bf16, staggered columns: conflict-free strided reads)
  #pragma unroll
  for (int j = 0; j < 64; ++j){
    const int e = tid + 512 * j;
    const int r = e >> 6, c = e & 63;
    x2s[r*64 + ((c + r) & 63)] = f2b_rne(x2g[(size_t)row0*64 + e]);
  }
  // ---- stage x1 (only columns n0..n0+7)
  #pragma unroll
  for (int j = 0; j < 8; ++j){
    const int e = tid + 512 * j;            // r*8 + c
    const int r = e >> 3, c = e & 7;
    x1s[e] = f2b_rne(x1g[(size_t)(row0 + r)*64 + n0 + c]);
  }

  // ---- this lane's two x3 rows -> packed bf16 (2 x 16 uints)
  uint32_t x3p[2][16];
  #pragma unroll
  for (int g = 0; g < 2; ++g){
    const int arow = row0 + wave*64 + g*32 + la;
    #pragma unroll
    for (int s = 0; s < 4; ++s){
      const float4 p0 = *(const float4*)(x3g + (size_t)arow*64 + s*16 + lg*8);
      const float4 p1 = *(const float4*)(x3g + (size_t)arow*64 + s*16 + lg*8 + 4);
      x3p[g][s*4+0] = (uint32_t)f2b_rne(p0.x) | ((uint32_t)f2b_rne(p0.y) << 16);
      x3p[g][s*4+1] = (uint32_t)f2b_rne(p0.z) | ((uint32_t)f2b_rne(p0.w) << 16);
      x3p[g][s*4+2] = (uint32_t)f2b_rne(p1.x) | ((uint32_t)f2b_rne(p1.y) << 16);
      x3p[g][s*4+3] = (uint32_t)f2b_rne(p1.z) | ((uint32_t)f2b_rne(p1.w) << 16);
    }
  }

  f32x16 acc[2][4];
  #pragma unroll
  for (int g = 0; g < 2; ++g)
    #pragma unroll
    for (int wn = 0; wn < 4; ++wn) acc[g][wn] = 0.f;

  const ushort* wbase = wsp + (size_t)n0 * 64 * 8192;

  // prologue: blk0 -> buf0, blk1 -> buf1
  #pragma unroll
  for (int pb = 0; pb < 2; ++pb){
    const char* sp = (const char*)wbase + (size_t)pb*16384 + wave*2048 + lane*16;
    char* dp = Bbuf + pb*16384 + wave*2048;
    __builtin_amdgcn_global_load_lds((const AS1 uint32_t*)sp,        (AS3 uint32_t*)dp,        16, 0, 0);
    __builtin_amdgcn_global_load_lds((const AS1 uint32_t*)(sp+1024), (AS3 uint32_t*)(dp+1024), 16, 0, 0);
  }
  __syncthreads();   // one-time full drain: x1s/x2s stores + blk0/blk1 DMA

  const int rl0 = wave*64 + la;
  const int rl1 = rl0 + 32;

  for (int t = 0; t < 512; ++t){           // 8 n x 64 m
    // issue DMA for blk t+2 into buf[(t+2)&3] (wrap source: harmless dummy)
    {
      const int nb = (t + 2) & 511;
      const char* sp = (const char*)wbase + (size_t)nb*16384 + wave*2048 + lane*16;
      char* dp = Bbuf + ((t + 2) & 3)*16384 + wave*2048;
      __builtin_amdgcn_global_load_lds((const AS1 uint32_t*)sp,        (AS3 uint32_t*)dp,        16, 0, 0);
      __builtin_amdgcn_global_load_lds((const AS1 uint32_t*)(sp+1024), (AS3 uint32_t*)(dp+1024), 16, 0, 0);
    }
    // counted wait: blk t's 2 loads (issued 2 iters ago) done; 4 stay in flight
    asm volatile("s_waitcnt vmcnt(4)\n\ts_barrier" ::: "memory");

    const int m  = t & 63;
    const int nc = t >> 6;
    const float c0 = __uint_as_float((uint32_t)x1s[rl0*8 + nc] << 16) *
                     __uint_as_float((uint32_t)x2s[rl0*64 + ((m + rl0) & 63)] << 16);
    const float c1 = __uint_as_float((uint32_t)x1s[rl1*8 + nc] << 16) *
                     __uint_as_float((uint32_t)x2s[rl1*64 + ((m + rl1) & 63)] << 16);

    const char* bb = Bbuf + (t & 3)*16384 + (lane << 4);
    #pragma unroll
    for (int s = 0; s < 4; ++s){
      ABFrag a0, a1;
      #pragma unroll
      for (int j = 0; j < 8; ++j){
        const uint32_t u0 = x3p[0][s*4 + (j >> 1)];
        const uint32_t u1 = x3p[1][s*4 + (j >> 1)];
        const float v0 = __uint_as_float((j & 1) ? (u0 & 0xFFFF0000u) : (u0 << 16));
        const float v1 = __uint_as_float((j & 1) ? (u1 & 0xFFFF0000u) : (u1 << 16));
        a0.h[j] = (__bf16)(c0 * v0);
        a1.h[j] = (__bf16)(c1 * v1);
      }
      #pragma unroll
      for (int wn = 0; wn < 4; ++wn){
        const s16x8 bf = *(const s16x8*)(bb + ((s*4 + wn) << 10));
        acc[0][wn] = __builtin_amdgcn_mfma_f32_32x32x16_bf16(a0.s, bf, acc[0][wn], 0, 0, 0);
        acc[1][wn] = __builtin_amdgcn_mfma_f32_32x32x16_bf16(a1.s, bf, acc[1][wn], 0, 0, 0);
      }
    }
  }

  // ---- epilogue: atomic accumulate split-K partials; split 0 carries bias
  #pragma unroll
  for (int g = 0; g < 2; ++g){
    #pragma unroll
    for (int wn = 0; wn < 4; ++wn){
      const int col = wn*32 + la;
      const float bv = (nsplit == 0) ? biasg[col] : 0.f;
      #pragma unroll
      for (int r = 0; r < 16; ++r){
        const int row = row0 + wave*64 + g*32 + (r & 3) + 8*(r >> 2) + 4*lg;
        atomicAdd(outg + (size_t)row*128 + col, acc[g][wn][r] + bv);
      }
    }
  }
}

// ---------------------------------------------------------------------------
extern "C" void kernel_launch(void* const* d_in, const int* in_sizes, int n_in,
                              void* d_out, int out_size, void* d_ws, size_t ws_size,
                              hipStream_t stream){
  const float* x1   = (const float*)d_in[0];
  const float* x2   = (const float*)d_in[1];
  const float* x3   = (const float*)d_in[2];
  const float* W    = (const float*)d_in[3];
  const float* bias = (const float*)d_in[4];
  float* out = (float*)d_out;

  // d_out is re-poisoned before every launch: zero it (split-K accumulates on top)
  hipMemsetAsync(d_out, 0, (size_t)16384 * 128 * sizeof(float), stream);

  // need 64 MB of scratch for the bf16-packed W
  if (ws_size < (size_t)64 * 1024 * 1024) return;

  ushort* wsp = (ushort*)d_ws;
  pack_w_kernel<<<2048, 256, 0, stream>>>(W, wsp);
  trilinear_gemm_kernel<<<256, 512, 0, stream>>>(x1, x2, x3, wsp, bias, out);
}

// Round 5
// 1030.138 us; speedup vs baseline: 2.1114x; 1.0555x over previous
//
#include <hip/hip_runtime.h>
#include <hip/hip_bf16.h>
#include <stdint.h>

#define AS1 __attribute__((address_space(1)))
#define AS3 __attribute__((address_space(3)))

typedef _Float16 f16x8 __attribute__((ext_vector_type(8)));
typedef _Float16 f16x2 __attribute__((ext_vector_type(2)));
typedef float f32x16 __attribute__((ext_vector_type(16)));

union AF { f16x8 v; f16x2 p[4]; };

__device__ __forceinline__ ushort f2h(float f){
  union { _Float16 h; ushort u; } cv; cv.h = (_Float16)f; return cv.u;
}
__device__ __forceinline__ _Float16 u2h(ushort u){
  union { _Float16 h; ushort u; } cv; cv.u = u; return cv.h;
}

// ---------------------------------------------------------------------------
// Pack W: fp32 [A=128][N=64][M=64][O=64] -> fp16 fragment-ordered stream.
// ws fp16 element index:
//   (n*64+m)*8192 + (s*4+wn)*512 + (g*32+la)*8 + i
//     = fp16( W[a=wn*32+la][n][m][o=s*16+g*8+i] )
// One block per (n,m): coalesced global read (lanes span o), XOR-swizzled LDS
// transpose, coalesced 16B chunk writes. 8192 fp16/block = 1024 chunks ->
// store loop is j<4 (round-4 bug: j<8 overran into block nm+1 = NaN garbage).
// ---------------------------------------------------------------------------
__global__ __launch_bounds__(256) void pack_w_kernel(const float* __restrict__ W,
                                                     ushort* __restrict__ wsp){
  __shared__ ushort lds[128 * 64];    // lds[a*64 + (o ^ ((a&7)<<3))] = h(W[a][o])
  const int nm  = blockIdx.x;         // n*64 + m
  const int n   = nm >> 6;
  const int m   = nm & 63;
  const int tid = threadIdx.x;
  const float* src = W + ((size_t)n << 12) + ((size_t)m << 6);  // + (a<<18) + o

  #pragma unroll
  for (int j = 0; j < 32; ++j){
    const int e = tid + 256 * j;      // a = e>>6, o = e&63 (=lane)
    const int a = e >> 6, o = e & 63;
    const float v = src[((size_t)a << 18) + o];
    lds[a*64 + (o ^ ((a & 7) << 3))] = f2h(v);
  }
  __syncthreads();

  ushort* dst = wsp + (size_t)nm * 8192;
  #pragma unroll
  for (int j = 0; j < 4; ++j){        // 1024 chunks of 8 halfwords
    const int c  = tid + 256 * j;
    const int f  = c >> 6;            // s*4 + wn
    const int q  = c & 63;            // g*32 + la
    const int wn = f & 3, s = f >> 2;
    const int g  = q >> 5, la = q & 31;
    const int a  = wn*32 + la;
    const int o0 = s*16 + g*8;
    *(uint4*)(dst + (size_t)c * 8) =
        *(const uint4*)(lds + a*64 + (o0 ^ ((a & 7) << 3)));
  }
}

// ---------------------------------------------------------------------------
// out[b,a] = sum_{n,m,o} x1[b,n] x2[b,m] x3[b,o] W[a,n,m,o] + bias[a]
// fp16 datapath: A-fragment = h(x1[n]*x2[m]) * h(x3[o]) via v_pk_mul_f16
// (32 VALU ops/lane/iter vs ~192 for the f32->bf16 path).
// BM=512: 8 waves x 64 rows (2 row-groups/wave) -> each B ds_read_b128 feeds
// two MFMAs (LDS read = 50% of MFMA budget). W quad-buffered, DMA issued
// 2 iters ahead, counted vmcnt(4) + raw s_barrier (no drain in main loop).
// 256 blocks = 1/CU, splitK=8, nsplit = bid&7 = XCD -> 32 lockstep blocks/XCD
// share one 8MB W octant in L2 (FETCH ~74MB total, round-3-verified).
// mfma_f32_32x32x16_f16; D layout: col=lane&31, row=(r&3)+8*(r>>2)+4*(lane>>5).
// ---------------------------------------------------------------------------
__global__ __launch_bounds__(512, 2) void trilinear_gemm_kernel(
    const float* __restrict__ x1g, const float* __restrict__ x2g,
    const float* __restrict__ x3g, const ushort* __restrict__ wsp,
    const float* __restrict__ biasg, float* __restrict__ outg){

  __shared__ __align__(16) char Bbuf[4 * 16384];   // 64 KB: W quad-buffer
  __shared__ ushort x2s[512 * 64];                 // 64 KB, staggered cols
  __shared__ ushort x1s[8 * 512];                  //  8 KB, [n][row] (2-way free)

  const int tid  = threadIdx.x;
  const int wave = tid >> 6;
  const int lane = tid & 63;
  const int la   = lane & 31;
  const int lg   = lane >> 5;

  const int bid    = blockIdx.x;
  const int nsplit = bid & 7;       // == XCD id under round-robin dispatch
  const int row0   = (bid >> 3) * 512;
  const int n0     = nsplit * 8;

  // ---- stage x2 tile (fp16, staggered columns: conflict-free strided reads)
  #pragma unroll
  for (int j = 0; j < 64; ++j){
    const int e = tid + 512 * j;
    const int r = e >> 6, c = e & 63;
    x2s[r*64 + ((c + r) & 63)] = f2h(x2g[(size_t)row0*64 + e]);
  }
  // ---- stage x1 transposed: x1s[nc][row]
  #pragma unroll
  for (int j = 0; j < 8; ++j)
    x1s[j*512 + tid] = f2h(x1g[(size_t)(row0 + tid)*64 + n0 + j]);

  // ---- this lane's two x3 rows -> fp16 pairs (2 x 16 VGPRs)
  f16x2 x3h[2][16];
  #pragma unroll
  for (int g = 0; g < 2; ++g){
    const int arow = row0 + wave*64 + g*32 + la;
    #pragma unroll
    for (int s = 0; s < 4; ++s){
      const float4 p0 = *(const float4*)(x3g + (size_t)arow*64 + s*16 + lg*8);
      const float4 p1 = *(const float4*)(x3g + (size_t)arow*64 + s*16 + lg*8 + 4);
      x3h[g][s*4+0] = f16x2{(_Float16)p0.x, (_Float16)p0.y};
      x3h[g][s*4+1] = f16x2{(_Float16)p0.z, (_Float16)p0.w};
      x3h[g][s*4+2] = f16x2{(_Float16)p1.x, (_Float16)p1.y};
      x3h[g][s*4+3] = f16x2{(_Float16)p1.z, (_Float16)p1.w};
    }
  }

  f32x16 acc[2][4];
  #pragma unroll
  for (int g = 0; g < 2; ++g)
    #pragma unroll
    for (int wn = 0; wn < 4; ++wn) acc[g][wn] = 0.f;

  const ushort* wbase = wsp + (size_t)n0 * 64 * 8192;

  // prologue: blk0 -> buf0, blk1 -> buf1
  #pragma unroll
  for (int pb = 0; pb < 2; ++pb){
    const char* sp = (const char*)wbase + (size_t)pb*16384 + wave*2048 + lane*16;
    char* dp = Bbuf + pb*16384 + wave*2048;
    __builtin_amdgcn_global_load_lds((const AS1 uint32_t*)sp,        (AS3 uint32_t*)dp,        16, 0, 0);
    __builtin_amdgcn_global_load_lds((const AS1 uint32_t*)(sp+1024), (AS3 uint32_t*)(dp+1024), 16, 0, 0);
  }
  __syncthreads();   // one-time full drain: x1s/x2s stores + blk0/blk1 DMA

  const int rl0 = wave*64 + la;
  const int rl1 = rl0 + 32;

  for (int t = 0; t < 512; ++t){           // 8 n x 64 m
    // issue DMA for blk t+2 into buf[(t+2)&3] (wrap source: harmless dummy)
    {
      const int nb = (t + 2) & 511;
      const char* sp = (const char*)wbase + (size_t)nb*16384 + wave*2048 + lane*16;
      char* dp = Bbuf + ((t + 2) & 3)*16384 + wave*2048;
      __builtin_amdgcn_global_load_lds((const AS1 uint32_t*)sp,        (AS3 uint32_t*)dp,        16, 0, 0);
      __builtin_amdgcn_global_load_lds((const AS1 uint32_t*)(sp+1024), (AS3 uint32_t*)(dp+1024), 16, 0, 0);
    }
    // counted wait: blk t's 2 loads (issued 2 iters ago) done; 4 stay in flight
    asm volatile("s_waitcnt vmcnt(4)\n\ts_barrier" ::: "memory");

    const int m  = t & 63;
    const int nc = t >> 6;
    const _Float16 h0 = u2h(x1s[nc*512 + rl0]) * u2h(x2s[rl0*64 + ((m + rl0) & 63)]);
    const _Float16 h1 = u2h(x1s[nc*512 + rl1]) * u2h(x2s[rl1*64 + ((m + rl1) & 63)]);
    const f16x2 hc0 = {h0, h0};
    const f16x2 hc1 = {h1, h1};

    const char* bb = Bbuf + (t & 3)*16384 + (lane << 4);
    #pragma unroll
    for (int s = 0; s < 4; ++s){
      AF a0, a1;
      #pragma unroll
      for (int jj = 0; jj < 4; ++jj){
        a0.p[jj] = hc0 * x3h[0][s*4 + jj];   // v_pk_mul_f16
        a1.p[jj] = hc1 * x3h[1][s*4 + jj];
      }
      #pragma unroll
      for (int wn = 0; wn < 4; ++wn){
        const f16x8 bf = *(const f16x8*)(bb + ((s*4 + wn) << 10));
        acc[0][wn] = __builtin_amdgcn_mfma_f32_32x32x16_f16(a0.v, bf, acc[0][wn], 0, 0, 0);
        acc[1][wn] = __builtin_amdgcn_mfma_f32_32x32x16_f16(a1.v, bf, acc[1][wn], 0, 0, 0);
      }
    }
  }

  // ---- epilogue: atomic accumulate split-K partials; split 0 carries bias
  #pragma unroll
  for (int g = 0; g < 2; ++g){
    #pragma unroll
    for (int wn = 0; wn < 4; ++wn){
      const int col = wn*32 + la;
      const float bv = (nsplit == 0) ? biasg[col] : 0.f;
      #pragma unroll
      for (int r = 0; r < 16; ++r){
        const int row = row0 + wave*64 + g*32 + (r & 3) + 8*(r >> 2) + 4*lg;
        atomicAdd(outg + (size_t)row*128 + col, acc[g][wn][r] + bv);
      }
    }
  }
}

// ---------------------------------------------------------------------------
extern "C" void kernel_launch(void* const* d_in, const int* in_sizes, int n_in,
                              void* d_out, int out_size, void* d_ws, size_t ws_size,
                              hipStream_t stream){
  const float* x1   = (const float*)d_in[0];
  const float* x2   = (const float*)d_in[1];
  const float* x3   = (const float*)d_in[2];
  const float* W    = (const float*)d_in[3];
  const float* bias = (const float*)d_in[4];
  float* out = (float*)d_out;

  // d_out is re-poisoned before every launch: zero it (split-K accumulates on top)
  hipMemsetAsync(d_out, 0, (size_t)16384 * 128 * sizeof(float), stream);

  // need 64 MB of scratch for the fp16-packed W
  if (ws_size < (size_t)64 * 1024 * 1024) return;

  ushort* wsp = (ushort*)d_ws;
  pack_w_kernel<<<4096, 256, 0, stream>>>(W, wsp);
  trilinear_gemm_kernel<<<256, 512, 0, stream>>>(x1, x2, x3, wsp, bias, out);
}

// Round 6
// 1018.486 us; speedup vs baseline: 2.1355x; 1.0114x over previous
//
#include <hip/hip_runtime.h>
#include <hip/hip_bf16.h>
#include <stdint.h>

#define AS1 __attribute__((address_space(1)))
#define AS3 __attribute__((address_space(3)))

typedef _Float16 f16x8 __attribute__((ext_vector_type(8)));
typedef _Float16 f16x2 __attribute__((ext_vector_type(2)));
typedef float f32x16 __attribute__((ext_vector_type(16)));

union AF { f16x8 v; f16x2 p[4]; };

__device__ __forceinline__ ushort f2h(float f){
  union { _Float16 h; ushort u; } cv; cv.h = (_Float16)f; return cv.u;
}
__device__ __forceinline__ _Float16 u2h(ushort u){
  union { _Float16 h; ushort u; } cv; cv.u = u; return cv.h;
}

// ---------------------------------------------------------------------------
// Pack W: fp32 [A=128][N=64][M=64][O=64] -> fp16 fragment-ordered stream.
// ws fp16 element index:
//   (n*64+m)*8192 + (s*4+wn)*512 + (g*32+la)*8 + i
//     = fp16( W[a=wn*32+la][n][m][o=s*16+g*8+i] )
// One block per (n,m): coalesced global read (lanes span o), XOR-swizzled LDS
// transpose, coalesced 16B chunk writes (1024 chunks -> j<4).
// ---------------------------------------------------------------------------
__global__ __launch_bounds__(256) void pack_w_kernel(const float* __restrict__ W,
                                                     ushort* __restrict__ wsp){
  __shared__ ushort lds[128 * 64];    // lds[a*64 + (o ^ ((a&7)<<3))] = h(W[a][o])
  const int nm  = blockIdx.x;         // n*64 + m
  const int n   = nm >> 6;
  const int m   = nm & 63;
  const int tid = threadIdx.x;
  const float* src = W + ((size_t)n << 12) + ((size_t)m << 6);  // + (a<<18) + o

  #pragma unroll
  for (int j = 0; j < 32; ++j){
    const int e = tid + 256 * j;      // a = e>>6, o = e&63 (=lane)
    const int a = e >> 6, o = e & 63;
    const float v = src[((size_t)a << 18) + o];
    lds[a*64 + (o ^ ((a & 7) << 3))] = f2h(v);
  }
  __syncthreads();

  ushort* dst = wsp + (size_t)nm * 8192;
  #pragma unroll
  for (int j = 0; j < 4; ++j){        // 1024 chunks of 8 halfwords
    const int c  = tid + 256 * j;
    const int f  = c >> 6;            // s*4 + wn
    const int q  = c & 63;            // g*32 + la
    const int wn = f & 3, s = f >> 2;
    const int g  = q >> 5, la = q & 31;
    const int a  = wn*32 + la;
    const int o0 = s*16 + g*8;
    *(uint4*)(dst + (size_t)c * 8) =
        *(const uint4*)(lds + a*64 + (o0 ^ ((a & 7) << 3)));
  }
}

// ---------------------------------------------------------------------------
// out[b,a] = sum_{n,m,o} x1[b,n] x2[b,m] x3[b,o] W[a,n,m,o] + bias[a]
// fp16 datapath, A-frag = h(x1*x2)*h(x3) via v_pk_mul_f16. BM=512, 8 waves x
// 64 rows. W quad-buffered, DMA depth 2, counted vmcnt(2) + raw s_barrier.
// SW-pipelined one iter ahead in SINGLE register sets (256-reg/wave cap at
// 8 waves/CU): S[4]=s0 B-frags, a0[2]=prebuilt A(s0), h=x1*x2 scalars ->
// barrier-exit is immediately MFMA-ready; s1..3 reads hide under MFMA phases.
// Trailing lgkmcnt(0) keeps cross-barrier prefetch WAR-airtight.
// 256 blocks = 1/CU, splitK=8, nsplit = bid&7 = XCD (L2-lockstep, FETCH 74MB).
// mfma_f32_32x32x16_f16; D layout: col=lane&31, row=(r&3)+8*(r>>2)+4*(lane>>5).
// ---------------------------------------------------------------------------
__global__ __launch_bounds__(512, 2) void trilinear_gemm_kernel(
    const float* __restrict__ x1g, const float* __restrict__ x2g,
    const float* __restrict__ x3g, const ushort* __restrict__ wsp,
    const float* __restrict__ biasg, float* __restrict__ outg){

  __shared__ __align__(16) char Bbuf[4 * 16384];   // 64 KB: W quad-buffer
  __shared__ ushort x2s[512 * 64];                 // 64 KB, staggered cols
  __shared__ ushort x1s[8 * 512];                  //  8 KB, [n][row]

  const int tid  = threadIdx.x;
  const int wave = tid >> 6;
  const int lane = tid & 63;
  const int la   = lane & 31;
  const int lg   = lane >> 5;

  const int bid    = blockIdx.x;
  const int nsplit = bid & 7;       // == XCD id under round-robin dispatch
  const int row0   = (bid >> 3) * 512;
  const int n0     = nsplit * 8;

  // ---- stage x2 tile (fp16, staggered columns)
  #pragma unroll
  for (int j = 0; j < 64; ++j){
    const int e = tid + 512 * j;
    const int r = e >> 6, c = e & 63;
    x2s[r*64 + ((c + r) & 63)] = f2h(x2g[(size_t)row0*64 + e]);
  }
  // ---- stage x1 transposed: x1s[nc][row]
  #pragma unroll
  for (int j = 0; j < 8; ++j)
    x1s[j*512 + tid] = f2h(x1g[(size_t)(row0 + tid)*64 + n0 + j]);

  // ---- this lane's two x3 rows -> fp16 pairs (2 x 16 VGPRs)
  f16x2 x3h[2][16];
  #pragma unroll
  for (int g = 0; g < 2; ++g){
    const int arow = row0 + wave*64 + g*32 + la;
    #pragma unroll
    for (int s = 0; s < 4; ++s){
      const float4 p0 = *(const float4*)(x3g + (size_t)arow*64 + s*16 + lg*8);
      const float4 p1 = *(const float4*)(x3g + (size_t)arow*64 + s*16 + lg*8 + 4);
      x3h[g][s*4+0] = f16x2{(_Float16)p0.x, (_Float16)p0.y};
      x3h[g][s*4+1] = f16x2{(_Float16)p0.z, (_Float16)p0.w};
      x3h[g][s*4+2] = f16x2{(_Float16)p1.x, (_Float16)p1.y};
      x3h[g][s*4+3] = f16x2{(_Float16)p1.z, (_Float16)p1.w};
    }
  }

  f32x16 acc[2][4];
  #pragma unroll
  for (int g = 0; g < 2; ++g)
    #pragma unroll
    for (int wn = 0; wn < 4; ++wn) acc[g][wn] = 0.f;

  const ushort* wbase = wsp + (size_t)n0 * 64 * 8192;

  // prologue: blk0 -> buf0, blk1 -> buf1
  #pragma unroll
  for (int pb = 0; pb < 2; ++pb){
    const char* sp = (const char*)wbase + (size_t)pb*16384 + wave*2048 + lane*16;
    char* dp = Bbuf + pb*16384 + wave*2048;
    __builtin_amdgcn_global_load_lds((const AS1 uint32_t*)sp,        (AS3 uint32_t*)dp,        16, 0, 0);
    __builtin_amdgcn_global_load_lds((const AS1 uint32_t*)(sp+1024), (AS3 uint32_t*)(dp+1024), 16, 0, 0);
  }
  __syncthreads();   // full drain: x1s/x2s stores + blk0/blk1 DMA

  const int rl0 = wave*64 + la;
  const int rl1 = rl0 + 32;

  // ---- pipelined state (single sets; consume-then-refill each iter)
  f16x8 S[4];                 // s=0 B-frags of current block
  AF a0[2];                   // prebuilt A(s=0) for current block
  _Float16 h0, h1;            // x1*x2 for current block

  {
    const char* bb0 = Bbuf + (lane << 4);
    #pragma unroll
    for (int wn = 0; wn < 4; ++wn) S[wn] = *(const f16x8*)(bb0 + (wn << 10));
    h0 = u2h(x1s[rl0]) * u2h(x2s[rl0*64 + (rl0 & 63)]);
    h1 = u2h(x1s[rl1]) * u2h(x2s[rl1*64 + (rl1 & 63)]);
    const f16x2 c0 = {h0, h0}, c1 = {h1, h1};
    #pragma unroll
    for (int jj = 0; jj < 4; ++jj){
      a0[0].p[jj] = c0 * x3h[0][jj];
      a0[1].p[jj] = c1 * x3h[1][jj];
    }
  }

  for (int t = 0; t < 512; ++t){           // 8 n x 64 m
    // issue DMA for blk t+2 into buf[(t+2)&3]
    {
      const int nd = (t + 2) & 511;
      const char* sp = (const char*)wbase + (size_t)nd*16384 + wave*2048 + lane*16;
      char* dp = Bbuf + ((t + 2) & 3)*16384 + wave*2048;
      __builtin_amdgcn_global_load_lds((const AS1 uint32_t*)sp,        (AS3 uint32_t*)dp,        16, 0, 0);
      __builtin_amdgcn_global_load_lds((const AS1 uint32_t*)(sp+1024), (AS3 uint32_t*)(dp+1024), 16, 0, 0);
    }
    // blk t+1 resident after this (its 2 loads are the oldest outstanding)
    asm volatile("s_waitcnt vmcnt(2)\n\ts_barrier" ::: "memory");

    const char* bbc = Bbuf + (t & 3)*16384 + (lane << 4);          // blk t
    const char* bbn = Bbuf + ((t + 1) & 3)*16384 + (lane << 4);    // blk t+1

    __builtin_amdgcn_s_setprio(1);
    // ---- s=0: fire immediately from prebuilt state
    #pragma unroll
    for (int wn = 0; wn < 4; ++wn){
      acc[0][wn] = __builtin_amdgcn_mfma_f32_32x32x16_f16(a0[0].v, S[wn], acc[0][wn], 0, 0, 0);
      acc[1][wn] = __builtin_amdgcn_mfma_f32_32x32x16_f16(a0[1].v, S[wn], acc[1][wn], 0, 0, 0);
    }
    // ---- refill S with blk t+1's s=0 frags (WAR on S orders after s=0 MFMAs)
    #pragma unroll
    for (int wn = 0; wn < 4; ++wn) S[wn] = *(const f16x8*)(bbn + (wn << 10));

    // ---- in-iter B-frag reads for s=1..3 of blk t
    f16x8 B1[4], B2[4], B3[4];
    #pragma unroll
    for (int wn = 0; wn < 4; ++wn) B1[wn] = *(const f16x8*)(bbc + ((4  + wn) << 10));
    #pragma unroll
    for (int wn = 0; wn < 4; ++wn) B2[wn] = *(const f16x8*)(bbc + ((8  + wn) << 10));
    #pragma unroll
    for (int wn = 0; wn < 4; ++wn) B3[wn] = *(const f16x8*)(bbc + ((12 + wn) << 10));

    // ---- u16 prefetch for blk t+1 (x1*x2 scalars)
    const int nb  = (t + 1) & 511;
    const int mn  = nb & 63, ncn = nb >> 6;
    const _Float16 hn0 = u2h(x1s[ncn*512 + rl0]) * u2h(x2s[rl0*64 + ((mn + rl0) & 63)]);
    const _Float16 hn1 = u2h(x1s[ncn*512 + rl1]) * u2h(x2s[rl1*64 + ((mn + rl1) & 63)]);

    const f16x2 c0 = {h0, h0}, c1 = {h1, h1};
    // ---- s=1..3 phases: build A (pk_mul) then 8 MFMAs each
    {
      AF a10, a11;
      #pragma unroll
      for (int jj = 0; jj < 4; ++jj){ a10.p[jj] = c0 * x3h[0][4 + jj]; a11.p[jj] = c1 * x3h[1][4 + jj]; }
      #pragma unroll
      for (int wn = 0; wn < 4; ++wn){
        acc[0][wn] = __builtin_amdgcn_mfma_f32_32x32x16_f16(a10.v, B1[wn], acc[0][wn], 0, 0, 0);
        acc[1][wn] = __builtin_amdgcn_mfma_f32_32x32x16_f16(a11.v, B1[wn], acc[1][wn], 0, 0, 0);
      }
    }
    {
      AF a20, a21;
      #pragma unroll
      for (int jj = 0; jj < 4; ++jj){ a20.p[jj] = c0 * x3h[0][8 + jj]; a21.p[jj] = c1 * x3h[1][8 + jj]; }
      #pragma unroll
      for (int wn = 0; wn < 4; ++wn){
        acc[0][wn] = __builtin_amdgcn_mfma_f32_32x32x16_f16(a20.v, B2[wn], acc[0][wn], 0, 0, 0);
        acc[1][wn] = __builtin_amdgcn_mfma_f32_32x32x16_f16(a21.v, B2[wn], acc[1][wn], 0, 0, 0);
      }
    }
    {
      AF a30, a31;
      #pragma unroll
      for (int jj = 0; jj < 4; ++jj){ a30.p[jj] = c0 * x3h[0][12 + jj]; a31.p[jj] = c1 * x3h[1][12 + jj]; }
      #pragma unroll
      for (int wn = 0; wn < 4; ++wn){
        acc[0][wn] = __builtin_amdgcn_mfma_f32_32x32x16_f16(a30.v, B3[wn], acc[0][wn], 0, 0, 0);
        acc[1][wn] = __builtin_amdgcn_mfma_f32_32x32x16_f16(a31.v, B3[wn], acc[1][wn], 0, 0, 0);
      }
    }
    __builtin_amdgcn_s_setprio(0);

    // ---- rotate pipelined state for blk t+1
    h0 = hn0; h1 = hn1;
    {
      const f16x2 d0 = {h0, h0}, d1 = {h1, h1};
      #pragma unroll
      for (int jj = 0; jj < 4; ++jj){
        a0[0].p[jj] = d0 * x3h[0][jj];
        a0[1].p[jj] = d1 * x3h[1][jj];
      }
    }
    // ensure S-refill + u16 reads have executed before we pass the next
    // barrier (keeps prefetch WAR-airtight vs. the DMA rewriting buffers)
    asm volatile("s_waitcnt lgkmcnt(0)" ::: "memory");
  }

  // ---- epilogue: atomic accumulate split-K partials; split 0 carries bias
  #pragma unroll
  for (int g = 0; g < 2; ++g){
    #pragma unroll
    for (int wn = 0; wn < 4; ++wn){
      const int col = wn*32 + la;
      const float bv = (nsplit == 0) ? biasg[col] : 0.f;
      #pragma unroll
      for (int r = 0; r < 16; ++r){
        const int row = row0 + wave*64 + g*32 + (r & 3) + 8*(r >> 2) + 4*lg;
        atomicAdd(outg + (size_t)row*128 + col, acc[g][wn][r] + bv);
      }
    }
  }
}

// ---------------------------------------------------------------------------
extern "C" void kernel_launch(void* const* d_in, const int* in_sizes, int n_in,
                              void* d_out, int out_size, void* d_ws, size_t ws_size,
                              hipStream_t stream){
  const float* x1   = (const float*)d_in[0];
  const float* x2   = (const float*)d_in[1];
  const float* x3   = (const float*)d_in[2];
  const float* W    = (const float*)d_in[3];
  const float* bias = (const float*)d_in[4];
  float* out = (float*)d_out;

  // d_out is re-poisoned before every launch: zero it (split-K accumulates on top)
  hipMemsetAsync(d_out, 0, (size_t)16384 * 128 * sizeof(float), stream);

  // need 64 MB of scratch for the fp16-packed W
  if (ws_size < (size_t)64 * 1024 * 1024) return;

  ushort* wsp = (ushort*)d_ws;
  pack_w_kernel<<<4096, 256, 0, stream>>>(W, wsp);
  trilinear_gemm_kernel<<<256, 512, 0, stream>>>(x1, x2, x3, wsp, bias, out);
}